// Round 4
// baseline (271.004 us; speedup 1.0000x reference)
//
#include <hip/hip_runtime.h>

#define NVV   778
#define NSEG  16
#define SEGSZ 49
#define GRIDN 32
#define BATCH 128
#define NPTS  (NSEG * SEGSZ)           // 784
#define VOLSZ (GRIDN * GRIDN * GRIDN)  // 32768 floats = 128 KB
#define NVOL  (2 * BATCH * NSEG)       // 4096
#define NBLK  256
#define VPB   (NVOL / NBLK)            // 16 volumes per persistent block

// Persistent blocks: 256 blocks x 1024 threads, one per CU (128 KB LDS).
// Register-prefetch double buffer across volumes. __launch_bounds__(1024,4):
// LDS already limits to 1 block/CU = 4 waves/SIMD, so tell the register
// allocator (VGPR cap 128) — without this the compiler targets 8 waves/SIMD
// (cap 64) and spills the 32-VGPR staging buffer to scratch (R3: +537 MB
// WRITE_SIZE, 2.4x slowdown).
__global__ __launch_bounds__(1024, 4) void sample_kernel(
    const float* __restrict__ vertices, const int* __restrict__ seg,
    const float* __restrict__ phiR, const float* __restrict__ phiL,
    float* __restrict__ loss)
{
    __shared__ float vol[VOLSZ];        // 128 KB
    __shared__ float wsum[16];
    __shared__ float sbox[4];           // cx, cy, cz, inv_scale

    const int tid = threadIdx.x;

    // ---- prologue: issue staging loads for volume 0 ----
    float4 stg[8];
    {
        int vid  = blockIdx.x;
        int k    = vid % NSEG;
        int b    = (vid / NSEG) % BATCH;
        int pass = vid / (NSEG * BATCH);
        const float* phi = (pass == 0 ? phiR : phiL) +
                           ((size_t)k * BATCH + b) * VOLSZ;
        #pragma unroll
        for (int i = 0; i < 8; ++i)
            stg[i] = *(const float4*)(phi + ((i * 1024 + tid) << 2));
    }

    for (int it = 0; it < VPB; ++it) {
        int vid  = blockIdx.x + NBLK * it;
        int k    = vid % NSEG;
        int b    = (vid / NSEG) % BATCH;
        int pass = vid / (NSEG * BATCH);
        int srcSide = (pass == 0) ? 1 : 0;   // pass0 samples LEFT vertices
        int boxSide = 1 - srcSide;           // with the OTHER side's boxes
        const float* vsrc = vertices + ((size_t)b * 2 + srcSide) * NVV * 3;
        const float* vbox = vertices + ((size_t)b * 2 + boxSide) * NVV * 3;

        // ---- box compute on wave 0 (current volume) ----
        if (tid < 64) {
            bool act = tid < SEGSZ;
            int vi = act ? seg[k * SEGSZ + tid] : 0;
            const float* v = vbox + (size_t)vi * 3;
            float x = v[0], y = v[1], z = v[2];
            float mnx = act ? x : 1e30f, mxx = act ? x : -1e30f;
            float mny = act ? y : 1e30f, mxy = act ? y : -1e30f;
            float mnz = act ? z : 1e30f, mxz = act ? z : -1e30f;
            #pragma unroll
            for (int m = 32; m; m >>= 1) {
                mnx = fminf(mnx, __shfl_xor(mnx, m));
                mxx = fmaxf(mxx, __shfl_xor(mxx, m));
                mny = fminf(mny, __shfl_xor(mny, m));
                mxy = fmaxf(mxy, __shfl_xor(mxy, m));
                mnz = fminf(mnz, __shfl_xor(mnz, m));
                mxz = fmaxf(mxz, __shfl_xor(mxz, m));
            }
            if (tid == 0) {
                sbox[0] = 0.5f * (mnx + mxx);
                sbox[1] = 0.5f * (mny + mxy);
                sbox[2] = 0.5f * (mnz + mxz);
                float ext = fmaxf(fmaxf(mxx - mnx, mxy - mny), mxz - mnz);
                sbox[3] = 1.0f / (0.55f * ext);   // (1+SCALE)*0.5 * ext
            }
        }

        // ---- commit staged registers to LDS (implicit vmcnt wait) ----
        #pragma unroll
        for (int i = 0; i < 8; ++i)
            *(float4*)&vol[(i * 1024 + tid) << 2] = stg[i];

        __syncthreads();   // (A) vol + sbox ready

        // ---- issue prefetch for NEXT volume (in flight during taps) ----
        if (it + 1 < VPB) {
            int nvid  = blockIdx.x + NBLK * (it + 1);
            int nk    = nvid % NSEG;
            int nb    = (nvid / NSEG) % BATCH;
            int npass = nvid / (NSEG * BATCH);
            const float* phin = (npass == 0 ? phiR : phiL) +
                                ((size_t)nk * BATCH + nb) * VOLSZ;
            #pragma unroll
            for (int i = 0; i < 8; ++i)
                stg[i] = *(const float4*)(phin + ((i * 1024 + tid) << 2));
        }

        // ---- trilinear taps from LDS ----
        float acc = 0.0f;
        if (tid < NPTS) {
            int vi = seg[tid];
            const float* v = vsrc + (size_t)vi * 3;
            float vx = v[0], vy = v[1], vz = v[2];
            float cx = sbox[0], cy = sbox[1], cz = sbox[2], invs = sbox[3];
            float fx = ((vx - cx) * invs + 1.0f) * 15.5f;
            float fy = ((vy - cy) * invs + 1.0f) * 15.5f;
            float fz = ((vz - cz) * invs + 1.0f) * 15.5f;
            if (!(fx <= -1.0f || fx >= 32.0f ||
                  fy <= -1.0f || fy >= 32.0f ||
                  fz <= -1.0f || fz >= 32.0f)) {
                float x0f = floorf(fx), y0f = floorf(fy), z0f = floorf(fz);
                float wx = fx - x0f, wy = fy - y0f, wz = fz - z0f;
                int x0 = (int)x0f, y0 = (int)y0f, z0 = (int)z0f;
                #pragma unroll
                for (int dz = 0; dz < 2; ++dz) {
                    int zz = z0 + dz;
                    if (zz < 0 || zz >= GRIDN) continue;
                    float wwz = dz ? wz : 1.0f - wz;
                    #pragma unroll
                    for (int dy = 0; dy < 2; ++dy) {
                        int yy = y0 + dy;
                        if (yy < 0 || yy >= GRIDN) continue;
                        float wzy = wwz * (dy ? wy : 1.0f - wy);
                        const float* row = vol + zz * (GRIDN * GRIDN) + yy * GRIDN;
                        #pragma unroll
                        for (int dx = 0; dx < 2; ++dx) {
                            int xx = x0 + dx;
                            if (xx < 0 || xx >= GRIDN) continue;
                            acc += wzy * (dx ? wx : 1.0f - wx) * row[xx];
                        }
                    }
                }
            }
        }

        // ---- block reduction ----
        #pragma unroll
        for (int off = 32; off; off >>= 1)
            acc += __shfl_down(acc, off);
        int wid  = tid >> 6;
        int lane = tid & 63;
        if (lane == 0) wsum[wid] = acc;
        __syncthreads();   // (B) wsum ready; everyone done reading vol
        if (tid == 0) {
            float tot = 0.f;
            #pragma unroll
            for (int i = 0; i < 16; ++i) tot += wsum[i];
            atomicAdd(loss + b, tot * 0.25f);
        }
        // next iteration's sync (A) protects vol/wsum reuse
    }
}

extern "C" void kernel_launch(void* const* d_in, const int* in_sizes, int n_in,
                              void* d_out, int out_size, void* d_ws, size_t ws_size,
                              hipStream_t stream) {
    const float* vertices = (const float*)d_in[0];
    const float* phiR     = (const float*)d_in[1];
    const float* phiL     = (const float*)d_in[2];
    const int*   seg      = (const int*)d_in[3];
    float* loss = (float*)d_out;

    hipMemsetAsync(d_out, 0, (size_t)out_size * sizeof(float), stream);

    sample_kernel<<<NBLK, 1024, 0, stream>>>(vertices, seg, phiR, phiL, loss);
}

// Round 5
// 125.404 us; speedup vs baseline: 2.1611x; 2.1611x over previous
//
#include <hip/hip_runtime.h>

#define NVV   778
#define NSEG  16
#define SEGSZ 49
#define GRIDN 32
#define BATCH 128
#define NPTS  (NSEG * SEGSZ)           // 784
#define VOLSZ (GRIDN * GRIDN * GRIDN)  // 32768 floats = 128 KB
#define NVOL  (2 * BATCH * NSEG)       // 4096
#define NBLK  256
#define VPB   (NVOL / NBLK)            // 16 volumes per persistent block

// Persistent blocks: 256 blocks x 1024 threads, one per CU (128 KB LDS).
// Register-prefetch double buffer across volumes.
// R3/R4 lesson (rule #20): a float4 stg[8] array got demoted to scratch
// (537 MB of scratch WRITE_SIZE, 2.4x slowdown) because the staging loops
// weren't fully unrolled -> dynamic indexing. Fix: NAMED registers
// stg0..stg7, hand-unrolled at all three sites.
#define STG_ISSUE(P) \
    stg0 = *(const float4*)((P) + 0 * 4096 + (tid << 2)); \
    stg1 = *(const float4*)((P) + 1 * 4096 + (tid << 2)); \
    stg2 = *(const float4*)((P) + 2 * 4096 + (tid << 2)); \
    stg3 = *(const float4*)((P) + 3 * 4096 + (tid << 2)); \
    stg4 = *(const float4*)((P) + 4 * 4096 + (tid << 2)); \
    stg5 = *(const float4*)((P) + 5 * 4096 + (tid << 2)); \
    stg6 = *(const float4*)((P) + 6 * 4096 + (tid << 2)); \
    stg7 = *(const float4*)((P) + 7 * 4096 + (tid << 2));

#define STG_COMMIT() \
    *(float4*)&vol[0 * 4096 + (tid << 2)] = stg0; \
    *(float4*)&vol[1 * 4096 + (tid << 2)] = stg1; \
    *(float4*)&vol[2 * 4096 + (tid << 2)] = stg2; \
    *(float4*)&vol[3 * 4096 + (tid << 2)] = stg3; \
    *(float4*)&vol[4 * 4096 + (tid << 2)] = stg4; \
    *(float4*)&vol[5 * 4096 + (tid << 2)] = stg5; \
    *(float4*)&vol[6 * 4096 + (tid << 2)] = stg6; \
    *(float4*)&vol[7 * 4096 + (tid << 2)] = stg7;

__global__ __launch_bounds__(1024, 4) void sample_kernel(
    const float* __restrict__ vertices, const int* __restrict__ seg,
    const float* __restrict__ phiR, const float* __restrict__ phiL,
    float* __restrict__ loss)
{
    __shared__ float vol[VOLSZ];        // 128 KB
    __shared__ float wsum[16];
    __shared__ float sbox[4];           // cx, cy, cz, inv_scale

    const int tid = threadIdx.x;

    float4 stg0, stg1, stg2, stg3, stg4, stg5, stg6, stg7;

    // ---- prologue: issue staging loads for volume 0 ----
    {
        int vid  = blockIdx.x;
        int k    = vid % NSEG;
        int b    = (vid / NSEG) % BATCH;
        int pass = vid / (NSEG * BATCH);
        const float* phi = (pass == 0 ? phiR : phiL) +
                           ((size_t)k * BATCH + b) * VOLSZ;
        STG_ISSUE(phi)
    }

    for (int it = 0; it < VPB; ++it) {
        int vid  = blockIdx.x + NBLK * it;
        int k    = vid % NSEG;
        int b    = (vid / NSEG) % BATCH;
        int pass = vid / (NSEG * BATCH);
        int srcSide = (pass == 0) ? 1 : 0;   // pass0 samples LEFT vertices
        int boxSide = 1 - srcSide;           // with the OTHER side's boxes
        const float* vsrc = vertices + ((size_t)b * 2 + srcSide) * NVV * 3;
        const float* vbox = vertices + ((size_t)b * 2 + boxSide) * NVV * 3;

        // ---- box compute on wave 0 (current volume) ----
        if (tid < 64) {
            bool act = tid < SEGSZ;
            int vi = act ? seg[k * SEGSZ + tid] : 0;
            const float* v = vbox + (size_t)vi * 3;
            float x = v[0], y = v[1], z = v[2];
            float mnx = act ? x : 1e30f, mxx = act ? x : -1e30f;
            float mny = act ? y : 1e30f, mxy = act ? y : -1e30f;
            float mnz = act ? z : 1e30f, mxz = act ? z : -1e30f;
            #pragma unroll
            for (int m = 32; m; m >>= 1) {
                mnx = fminf(mnx, __shfl_xor(mnx, m));
                mxx = fmaxf(mxx, __shfl_xor(mxx, m));
                mny = fminf(mny, __shfl_xor(mny, m));
                mxy = fmaxf(mxy, __shfl_xor(mxy, m));
                mnz = fminf(mnz, __shfl_xor(mnz, m));
                mxz = fmaxf(mxz, __shfl_xor(mxz, m));
            }
            if (tid == 0) {
                sbox[0] = 0.5f * (mnx + mxx);
                sbox[1] = 0.5f * (mny + mxy);
                sbox[2] = 0.5f * (mnz + mxz);
                float ext = fmaxf(fmaxf(mxx - mnx, mxy - mny), mxz - mnz);
                sbox[3] = 1.0f / (0.55f * ext);   // (1+SCALE)*0.5 * ext
            }
        }

        // ---- commit staged registers to LDS (vmcnt wait happens here) ----
        STG_COMMIT()

        __syncthreads();   // (A) vol + sbox ready

        // ---- issue prefetch for NEXT volume (in flight during taps) ----
        if (it + 1 < VPB) {
            int nvid  = blockIdx.x + NBLK * (it + 1);
            int nk    = nvid % NSEG;
            int nb    = (nvid / NSEG) % BATCH;
            int npass = nvid / (NSEG * BATCH);
            const float* phin = (npass == 0 ? phiR : phiL) +
                                ((size_t)nk * BATCH + nb) * VOLSZ;
            STG_ISSUE(phin)
        }

        // ---- trilinear taps from LDS ----
        float acc = 0.0f;
        if (tid < NPTS) {
            int vi = seg[tid];
            const float* v = vsrc + (size_t)vi * 3;
            float vx = v[0], vy = v[1], vz = v[2];
            float cx = sbox[0], cy = sbox[1], cz = sbox[2], invs = sbox[3];
            float fx = ((vx - cx) * invs + 1.0f) * 15.5f;
            float fy = ((vy - cy) * invs + 1.0f) * 15.5f;
            float fz = ((vz - cz) * invs + 1.0f) * 15.5f;
            if (!(fx <= -1.0f || fx >= 32.0f ||
                  fy <= -1.0f || fy >= 32.0f ||
                  fz <= -1.0f || fz >= 32.0f)) {
                float x0f = floorf(fx), y0f = floorf(fy), z0f = floorf(fz);
                float wx = fx - x0f, wy = fy - y0f, wz = fz - z0f;
                int x0 = (int)x0f, y0 = (int)y0f, z0 = (int)z0f;
                #pragma unroll
                for (int dz = 0; dz < 2; ++dz) {
                    int zz = z0 + dz;
                    if (zz < 0 || zz >= GRIDN) continue;
                    float wwz = dz ? wz : 1.0f - wz;
                    #pragma unroll
                    for (int dy = 0; dy < 2; ++dy) {
                        int yy = y0 + dy;
                        if (yy < 0 || yy >= GRIDN) continue;
                        float wzy = wwz * (dy ? wy : 1.0f - wy);
                        const float* row = vol + zz * (GRIDN * GRIDN) + yy * GRIDN;
                        #pragma unroll
                        for (int dx = 0; dx < 2; ++dx) {
                            int xx = x0 + dx;
                            if (xx < 0 || xx >= GRIDN) continue;
                            acc += wzy * (dx ? wx : 1.0f - wx) * row[xx];
                        }
                    }
                }
            }
        }

        // ---- block reduction ----
        #pragma unroll
        for (int off = 32; off; off >>= 1)
            acc += __shfl_down(acc, off);
        int wid  = tid >> 6;
        int lane = tid & 63;
        if (lane == 0) wsum[wid] = acc;
        __syncthreads();   // (B) wsum ready; everyone done reading vol
        if (tid == 0) {
            float tot = 0.f;
            #pragma unroll
            for (int i = 0; i < 16; ++i) tot += wsum[i];
            atomicAdd(loss + b, tot * 0.25f);
        }
        // next iteration's sync (A) protects vol/wsum reuse
    }
}

extern "C" void kernel_launch(void* const* d_in, const int* in_sizes, int n_in,
                              void* d_out, int out_size, void* d_ws, size_t ws_size,
                              hipStream_t stream) {
    const float* vertices = (const float*)d_in[0];
    const float* phiR     = (const float*)d_in[1];
    const float* phiL     = (const float*)d_in[2];
    const int*   seg      = (const int*)d_in[3];
    float* loss = (float*)d_out;

    hipMemsetAsync(d_out, 0, (size_t)out_size * sizeof(float), stream);

    sample_kernel<<<NBLK, 1024, 0, stream>>>(vertices, seg, phiR, phiL, loss);
}

// Round 6
// 123.493 us; speedup vs baseline: 2.1945x; 1.0155x over previous
//
#include <hip/hip_runtime.h>

#define NVV   778
#define NSEG  16
#define SEGSZ 49
#define GRIDN 32
#define BATCH 128
#define NPTS  (NSEG * SEGSZ)           // 784
#define VOLSZ (GRIDN * GRIDN * GRIDN)  // 32768 floats = 128 KB
#define NVOL  (2 * BATCH * NSEG)       // 4096
#define NBLK  256
#define VPB   (NVOL / NBLK)            // 16 volumes per persistent block

// ---- named-register staging (rule #20: never index staging arrays) ----
#define STG_ISSUE(S, P) \
    S##0 = *(const float4*)((P) + 0 * 4096 + (tid << 2)); \
    S##1 = *(const float4*)((P) + 1 * 4096 + (tid << 2)); \
    S##2 = *(const float4*)((P) + 2 * 4096 + (tid << 2)); \
    S##3 = *(const float4*)((P) + 3 * 4096 + (tid << 2)); \
    S##4 = *(const float4*)((P) + 4 * 4096 + (tid << 2)); \
    S##5 = *(const float4*)((P) + 5 * 4096 + (tid << 2)); \
    S##6 = *(const float4*)((P) + 6 * 4096 + (tid << 2)); \
    S##7 = *(const float4*)((P) + 7 * 4096 + (tid << 2));

#define STG_COMMIT(S) \
    *(float4*)&vol[0 * 4096 + (tid << 2)] = S##0; \
    *(float4*)&vol[1 * 4096 + (tid << 2)] = S##1; \
    *(float4*)&vol[2 * 4096 + (tid << 2)] = S##2; \
    *(float4*)&vol[3 * 4096 + (tid << 2)] = S##3; \
    *(float4*)&vol[4 * 4096 + (tid << 2)] = S##4; \
    *(float4*)&vol[5 * 4096 + (tid << 2)] = S##5; \
    *(float4*)&vol[6 * 4096 + (tid << 2)] = S##6; \
    *(float4*)&vol[7 * 4096 + (tid << 2)] = S##7;

// load next iter's point-vertex coords into (nx,ny,nz)
#define PV_LOAD(IT, nx, ny, nz) \
    if ((IT) < VPB && tid < NPTS) { \
        int vid_ = bx + NBLK * (IT); \
        int b_   = (vid_ >> 4) & (BATCH - 1); \
        int src_ = (vid_ >> 11) == 0 ? 1 : 0; \
        const float* v_ = vertices + (((size_t)b_ * 2 + src_) * NVV + pvi) * 3; \
        nx = v_[0]; ny = v_[1]; nz = v_[2]; \
    }

// taps + block reduce + atomic for iteration IT (expects pvx/pvy/pvz current)
#define TAPS_REDUCE(IT) { \
    float acc = 0.0f; \
    if (tid < NPTS) { \
        float4 bx4 = sbox[IT]; \
        float fx = ((pvx - bx4.x) * bx4.w + 1.0f) * 15.5f; \
        float fy = ((pvy - bx4.y) * bx4.w + 1.0f) * 15.5f; \
        float fz = ((pvz - bx4.z) * bx4.w + 1.0f) * 15.5f; \
        if (!(fx <= -1.0f || fx >= 32.0f || \
              fy <= -1.0f || fy >= 32.0f || \
              fz <= -1.0f || fz >= 32.0f)) { \
            float x0f = floorf(fx), y0f = floorf(fy), z0f = floorf(fz); \
            float wx = fx - x0f, wy = fy - y0f, wz = fz - z0f; \
            int x0 = (int)x0f, y0 = (int)y0f, z0 = (int)z0f; \
            _Pragma("unroll") \
            for (int dz = 0; dz < 2; ++dz) { \
                int zz = z0 + dz; \
                if (zz < 0 || zz >= GRIDN) continue; \
                float wwz = dz ? wz : 1.0f - wz; \
                _Pragma("unroll") \
                for (int dy = 0; dy < 2; ++dy) { \
                    int yy = y0 + dy; \
                    if (yy < 0 || yy >= GRIDN) continue; \
                    float wzy = wwz * (dy ? wy : 1.0f - wy); \
                    const float* row = vol + zz * (GRIDN * GRIDN) + yy * GRIDN; \
                    _Pragma("unroll") \
                    for (int dx = 0; dx < 2; ++dx) { \
                        int xx = x0 + dx; \
                        if (xx < 0 || xx >= GRIDN) continue; \
                        acc += wzy * (dx ? wx : 1.0f - wx) * row[xx]; \
                    } \
                } \
            } \
        } \
    } \
    _Pragma("unroll") \
    for (int off = 32; off; off >>= 1) acc += __shfl_down(acc, off); \
    if (lane == 0) wsum[wv] = acc; \
    __syncthreads(); /* wsum ready; all taps done -> vol reusable */ \
    if (tid == 0) { \
        float tot = 0.f; \
        _Pragma("unroll") \
        for (int i = 0; i < 16; ++i) tot += wsum[i]; \
        int vid_ = bx + NBLK * (IT); \
        atomicAdd(loss + ((vid_ >> 4) & (BATCH - 1)), tot * 0.25f); \
    } }

// Persistent: 256 blocks x 1024 threads (1/CU, 128 KB LDS). 2-deep A/B
// register staging: commit of buffer A waits only on A's loads (counted
// vmcnt) while B's 8 loads remain in flight -> HBM queue never drains.
// All boxes precomputed in prologue (wave w -> iter w, overlaps volume-0
// stream); point coords double-buffered one iter ahead.
__global__ __launch_bounds__(1024, 4) void sample_kernel(
    const float* __restrict__ vertices, const int* __restrict__ seg,
    const float* __restrict__ phiR, const float* __restrict__ phiL,
    float* __restrict__ loss)
{
    __shared__ float vol[VOLSZ];        // 128 KB
    __shared__ float4 sbox[VPB];        // per-iter center.xyz, inv_scale
    __shared__ float wsum[16];

    const int tid = threadIdx.x;
    const int bx  = blockIdx.x;
    const int k   = bx & (NSEG - 1);    // 256 % 16 == 0 -> k const per block
    const int wv  = tid >> 6;
    const int lane = tid & 63;

    float4 a0, a1, a2, a3, a4, a5, a6, a7;
    float4 b0, b1, b2, b3, b4, b5, b6, b7;

    // phi base for iteration it
    auto phiPtr = [&](int it) {
        int vid  = bx + NBLK * it;
        int b    = (vid >> 4) & (BATCH - 1);
        int pass = vid >> 11;            // NSEG*BATCH = 2048
        return (pass == 0 ? phiR : phiL) + ((size_t)k * BATCH + b) * VOLSZ;
    };

    // ---- prologue: fill the pipe with volumes 0 and 1 ----
    STG_ISSUE(a, phiPtr(0))
    STG_ISSUE(b, phiPtr(1))

    // point-vertex index (independent of iter: flat seg[0..783])
    int pvi = (tid < NPTS) ? seg[tid] : 0;

    // all 16 boxes: wave w computes iter w's box (overlaps streaming)
    {
        int vid  = bx + NBLK * wv;
        int bb   = (vid >> 4) & (BATCH - 1);
        int pass = vid >> 11;
        int boxSide = (pass == 0) ? 0 : 1;   // opposite of src side
        const float* vbox = vertices + ((size_t)bb * 2 + boxSide) * NVV * 3;
        bool act = lane < SEGSZ;
        int vi = act ? seg[k * SEGSZ + lane] : 0;
        const float* v = vbox + (size_t)vi * 3;
        float x = v[0], y = v[1], z = v[2];
        float mnx = act ? x : 1e30f, mxx = act ? x : -1e30f;
        float mny = act ? y : 1e30f, mxy = act ? y : -1e30f;
        float mnz = act ? z : 1e30f, mxz = act ? z : -1e30f;
        #pragma unroll
        for (int m = 32; m; m >>= 1) {
            mnx = fminf(mnx, __shfl_xor(mnx, m));
            mxx = fmaxf(mxx, __shfl_xor(mxx, m));
            mny = fminf(mny, __shfl_xor(mny, m));
            mxy = fmaxf(mxy, __shfl_xor(mxy, m));
            mnz = fminf(mnz, __shfl_xor(mnz, m));
            mxz = fmaxf(mxz, __shfl_xor(mxz, m));
        }
        if (lane == 0) {
            float ext = fmaxf(fmaxf(mxx - mnx, mxy - mny), mxz - mnz);
            sbox[wv] = make_float4(0.5f * (mnx + mxx), 0.5f * (mny + mxy),
                                   0.5f * (mnz + mxz), 1.0f / (0.55f * ext));
        }
    }

    // iter-0 point coords
    float pvx = 0.f, pvy = 0.f, pvz = 0.f;
    float nvx = 0.f, nvy = 0.f, nvz = 0.f;
    PV_LOAD(0, pvx, pvy, pvz)

    __syncthreads();   // sbox ready

    for (int it = 0; it < VPB; it += 2) {
        // ---- even iter: volume it lives in A ----
        STG_COMMIT(a)                        // waits A's loads; B in flight
        __syncthreads();                     // vol ready
        if (it + 2 < VPB) { STG_ISSUE(a, phiPtr(it + 2)) }
        PV_LOAD(it + 1, nvx, nvy, nvz)       // next iter's points, early
        TAPS_REDUCE(it)
        pvx = nvx; pvy = nvy; pvz = nvz;

        // ---- odd iter: volume it+1 lives in B ----
        STG_COMMIT(b)
        __syncthreads();
        if (it + 3 < VPB) { STG_ISSUE(b, phiPtr(it + 3)) }
        PV_LOAD(it + 2, nvx, nvy, nvz)
        TAPS_REDUCE(it + 1)
        pvx = nvx; pvy = nvy; pvz = nvz;
    }
}

extern "C" void kernel_launch(void* const* d_in, const int* in_sizes, int n_in,
                              void* d_out, int out_size, void* d_ws, size_t ws_size,
                              hipStream_t stream) {
    const float* vertices = (const float*)d_in[0];
    const float* phiR     = (const float*)d_in[1];
    const float* phiL     = (const float*)d_in[2];
    const int*   seg      = (const int*)d_in[3];
    float* loss = (float*)d_out;

    hipMemsetAsync(d_out, 0, (size_t)out_size * sizeof(float), stream);

    sample_kernel<<<NBLK, 1024, 0, stream>>>(vertices, seg, phiR, phiL, loss);
}

// Round 7
// 106.408 us; speedup vs baseline: 2.5469x; 1.1606x over previous
//
#include <hip/hip_runtime.h>

#define NVV   778
#define NSEG  16
#define SEGSZ 49
#define GRIDN 32
#define BATCH 128
#define NPTS  (NSEG * SEGSZ)           // 784
#define VOLSZ (GRIDN * GRIDN * GRIDN)  // 32768 floats = 128 KB
#define NVOL  (2 * BATCH * NSEG)       // 4096
#define NBLK  256
#define VPB   (NVOL / NBLK)            // 16 volumes per persistent block

// z-split halves: R0 = slabs 0..15 (serves z0 in [-1,14]),
//                 R1 = slabs 15..31 (serves z0 in [15,31]); slab 15 duplicated.
#define H0_FLOATS (16 * 1024)          // 64 KB
#define H1_FLOATS (17 * 1024)          // 68 KB
#define H0_CHUNKS (H0_FLOATS / 256)    // 64 x 1KB wave-chunks
#define H1_CHUNKS (H1_FLOATS / 256)    // 68

typedef __attribute__((address_space(1))) const void* as1_t;
typedef __attribute__((address_space(3))) void* as3_t;

// async global->LDS DMA: no VGPR destination, so the compiler cannot sink
// these loads to a later use (R5/R6 failure mode). LDS dest is wave-uniform
// base + lane*16 (HW); global src is per-lane.
#define STREAM(DST, SRC, NCH) \
    for (int c = wv; c < (NCH); c += 16) { \
        __builtin_amdgcn_global_load_lds( \
            (as1_t)((SRC) + c * 256 + lane * 4), \
            (as3_t)((DST) + c * 256), 16, 0, 0); \
    }

// load volume IT's point-vertex coords into (nx,ny,nz)
#define PV_LOAD(IT, nx, ny, nz) \
    if ((IT) < VPB && tid < NPTS) { \
        int vid_ = bx + NBLK * (IT); \
        int b_   = (vid_ >> 4) & (BATCH - 1); \
        int src_ = (vid_ >> 11) == 0 ? 1 : 0; \
        const float* v_ = vertices + (((size_t)b_ * 2 + src_) * NVV + pvi) * 3; \
        nx = v_[0]; ny = v_[1]; nz = v_[2]; \
    }

// 2x4 taps of one z-half. base: LDS half; zrel0: z0 - zbase.
__device__ __forceinline__ float taps_half(
    const float* base, int zrel0, bool z0ok, bool z1ok,
    int x0, int y0, float wx, float wy, float wz)
{
    float s = 0.f;
    #pragma unroll
    for (int dz = 0; dz < 2; ++dz) {
        if (!(dz ? z1ok : z0ok)) continue;
        float wwz = dz ? wz : 1.f - wz;
        const float* slab = base + (zrel0 + dz) * (GRIDN * GRIDN);
        #pragma unroll
        for (int dy = 0; dy < 2; ++dy) {
            int yy = y0 + dy;
            if (yy < 0 || yy >= GRIDN) continue;
            float wzy = wwz * (dy ? wy : 1.f - wy);
            const float* row = slab + yy * GRIDN;
            #pragma unroll
            for (int dx = 0; dx < 2; ++dx) {
                int xx = x0 + dx;
                if (xx < 0 || xx >= GRIDN) continue;
                s += wzy * (dx ? wx : 1.f - wx) * row[xx];
            }
        }
    }
    return s;
}

// Persistent: 256 blocks x 1024 threads (1/CU, 135 KB LDS). Per volume,
// two phases; each phase overlaps a ~66 KB async LDS stream of the NEXT
// half with trilinear taps on the CURRENT half. The __syncthreads vmcnt(0)
// drain is the phase-boundary wait.
__global__ __launch_bounds__(1024, 4) void sample_kernel(
    const float* __restrict__ vertices, const int* __restrict__ seg,
    const float* __restrict__ phiR, const float* __restrict__ phiL,
    float* __restrict__ loss)
{
    __shared__ __align__(16) float R0[H0_FLOATS];   // slabs 0..15
    __shared__ __align__(16) float R1[H1_FLOATS];   // slabs 15..31
    __shared__ float4 sbox[VPB];
    __shared__ float wsum[16];

    const int tid  = threadIdx.x;
    const int bx   = blockIdx.x;
    const int k    = bx & (NSEG - 1);    // constant per block (256 % 16 == 0)
    const int wv   = tid >> 6;
    const int lane = tid & 63;

    auto phiPtr = [&](int it) {
        int vid  = bx + NBLK * it;
        int b    = (vid >> 4) & (BATCH - 1);
        int pass = vid >> 11;            // NSEG*BATCH = 2048
        return (pass == 0 ? phiR : phiL) + ((size_t)k * BATCH + b) * VOLSZ;
    };

    // ---- prologue: stream h0 of volume 0 into R0 ----
    {
        const float* p0 = phiPtr(0);
        STREAM(R0, p0, H0_CHUNKS)
    }

    int pvi = (tid < NPTS) ? seg[tid] : 0;

    // all 16 boxes: wave w computes volume w's box (overlaps the stream)
    {
        int vid  = bx + NBLK * wv;
        int bb   = (vid >> 4) & (BATCH - 1);
        int pass = vid >> 11;
        int boxSide = (pass == 0) ? 0 : 1;   // opposite of sampled side
        const float* vbox = vertices + ((size_t)bb * 2 + boxSide) * NVV * 3;
        bool act = lane < SEGSZ;
        int vi = act ? seg[k * SEGSZ + lane] : 0;
        const float* v = vbox + (size_t)vi * 3;
        float x = v[0], y = v[1], z = v[2];
        float mnx = act ? x : 1e30f, mxx = act ? x : -1e30f;
        float mny = act ? y : 1e30f, mxy = act ? y : -1e30f;
        float mnz = act ? z : 1e30f, mxz = act ? z : -1e30f;
        #pragma unroll
        for (int m = 32; m; m >>= 1) {
            mnx = fminf(mnx, __shfl_xor(mnx, m));
            mxx = fmaxf(mxx, __shfl_xor(mxx, m));
            mny = fminf(mny, __shfl_xor(mny, m));
            mxy = fmaxf(mxy, __shfl_xor(mxy, m));
            mnz = fminf(mnz, __shfl_xor(mnz, m));
            mxz = fmaxf(mxz, __shfl_xor(mxz, m));
        }
        if (lane == 0) {
            float ext = fmaxf(fmaxf(mxx - mnx, mxy - mny), mxz - mnz);
            sbox[wv] = make_float4(0.5f * (mnx + mxx), 0.5f * (mny + mxy),
                                   0.5f * (mnz + mxz), 1.0f / (0.55f * ext));
        }
    }

    float pvx = 0.f, pvy = 0.f, pvz = 0.f;
    float nvx = 0.f, nvy = 0.f, nvz = 0.f;
    PV_LOAD(0, pvx, pvy, pvz)

    __syncthreads();   // R0 streamed, sbox ready

    for (int v = 0; v < VPB; ++v) {
        const float* pv_phi = phiPtr(v);

        // ---- phase A: stream slabs 15..31 of v -> R1; taps z0<=14 from R0 --
        STREAM(R1, pv_phi + 15 * 1024, H1_CHUNKS)

        float fx = 0.f, fy = 0.f, fz = -2.f;
        if (tid < NPTS) {
            float4 b4 = sbox[v];
            fx = ((pvx - b4.x) * b4.w + 1.f) * 15.5f;
            fy = ((pvy - b4.y) * b4.w + 1.f) * 15.5f;
            fz = ((pvz - b4.z) * b4.w + 1.f) * 15.5f;
        }
        PV_LOAD(v + 1, nvx, nvy, nvz)

        bool inxy = (fx > -1.f && fx < 32.f && fy > -1.f && fy < 32.f);
        float x0f = floorf(fx), y0f = floorf(fy), z0f = floorf(fz);
        float wx = fx - x0f, wy = fy - y0f, wz = fz - z0f;
        int x0 = (int)x0f, y0 = (int)y0f, z0 = (int)z0f;

        float acc = 0.f;
        if (inxy && fz > -1.f && fz < 15.f)          // z0 in [-1,14]
            acc += taps_half(R0, z0, z0 >= 0, true, x0, y0, wx, wy, wz);

        __syncthreads();   // R1 ready; everyone done with R0

        // ---- phase B: stream slabs 0..15 of v+1 -> R0; taps z0>=15 from R1 -
        if (v + 1 < VPB) {
            const float* pn_phi = phiPtr(v + 1);
            STREAM(R0, pn_phi, H0_CHUNKS)
        }
        if (inxy && fz >= 15.f && fz < 32.f)         // z0 in [15,31]
            acc += taps_half(R1, z0 - 15, true, z0 + 1 < GRIDN, x0, y0, wx, wy, wz);

        // ---- per-volume block reduction ----
        #pragma unroll
        for (int off = 32; off; off >>= 1)
            acc += __shfl_down(acc, off);
        if (lane == 0) wsum[wv] = acc;
        __syncthreads();   // R0 ready; R1 free; wsum visible
        if (tid == 0) {
            float tot = 0.f;
            #pragma unroll
            for (int i = 0; i < 16; ++i) tot += wsum[i];
            int vid = bx + NBLK * v;
            atomicAdd(loss + ((vid >> 4) & (BATCH - 1)), tot * 0.25f);
        }
        pvx = nvx; pvy = nvy; pvz = nvz;
    }
}

extern "C" void kernel_launch(void* const* d_in, const int* in_sizes, int n_in,
                              void* d_out, int out_size, void* d_ws, size_t ws_size,
                              hipStream_t stream) {
    const float* vertices = (const float*)d_in[0];
    const float* phiR     = (const float*)d_in[1];
    const float* phiL     = (const float*)d_in[2];
    const int*   seg      = (const int*)d_in[3];
    float* loss = (float*)d_out;

    hipMemsetAsync(d_out, 0, (size_t)out_size * sizeof(float), stream);

    sample_kernel<<<NBLK, 1024, 0, stream>>>(vertices, seg, phiR, phiL, loss);
}